// Round 22
// baseline (203.197 us; speedup 1.0000x reference)
//
#include <hip/hip_runtime.h>
#include <math.h>

#define CH 64
#define S 64
#define S2 (64 * 64)
#define S3 (64 * 64 * 64)

typedef short short8_t __attribute__((ext_vector_type(8)));
typedef float float4_t __attribute__((ext_vector_type(4)));

__device__ __align__(16) unsigned short WB_buf[CH * CH];   // bf16 W[o][c]
__device__ __align__(16) unsigned short peT_buf[32 * 64];  // bf16 peT[t][c], t>=27 zero

__device__ __forceinline__ unsigned short f2bf(float f) {  // RNE to bf16
  unsigned int u = __float_as_uint(f);
  return (unsigned short)((u + 0x7FFFu + ((u >> 16) & 1u)) >> 16);
}

// ---------------------------------------------------------------------------
// Kernel 0: W -> bf16 row-major; pe -> bf16 transposed [t][c] padded to 32 t.
// ---------------------------------------------------------------------------
__global__ __launch_bounds__(256) void wprep(const float* __restrict__ W,
                                             const float* __restrict__ pe) {
  int i = blockIdx.x * 256 + threadIdx.x;  // 0..6143
  if (i < 4096) {
    WB_buf[i] = f2bf(W[i]);
  } else {
    int j = i - 4096;  // 0..2047
    int t = j >> 6, c = j & 63;
    peT_buf[t * 64 + c] = (t < 27) ? f2bf(pe[c * 27 + t]) : (unsigned short)0;
  }
}

// ---------------------------------------------------------------------------
// Fused kernel (r21 + MLP widening): in phases A and B all 20 loads of a
// channel-pair are issued BEFORE any FMA of the pair (was load/compute
// interleaved per channel) -> ~40 outstanding loads with unroll 2, hiding
// more of the L2/HBM latency at fixed (register-capped ~2.5 waves/SIMD)
// occupancy. Everything else identical to r21.
// ---------------------------------------------------------------------------
__global__ __launch_bounds__(256) void attn_fused(const float* __restrict__ Q,
                                                  const float* __restrict__ K,
                                                  const float* __restrict__ V,
                                                  const float* __restrict__ bias,
                                                  float* __restrict__ out) {
  __shared__ unsigned short xs[4][CH][68];  // 34816 B (time-shared: Q/spe/x)
  int tid = threadIdx.x;
  int lane = tid & 63;
  int wv = tid >> 6;

  // XCD-aware bijective swizzle (2048 % 8 == 0)
  int raw = blockIdx.x;
  int sw = (raw & 7) * 256 + (raw >> 3);
  int b = sw >> 10;
  int r = sw & 1023;
  int d = r >> 4;                                             // 0..63
  int hu = __builtin_amdgcn_readfirstlane((r & 15) * 4 + wv);  // 0..63, uniform

  size_t bbase = (size_t)b << 24;
  const float* Qb = Q + bbase;
  const float* Kb = K + bbase;
  const float* Vb = V + bbase;
  float* outb = out + bbase;

  float lmL = (lane == 0) ? 0.f : 1.f;
  float lmR = (lane == 63) ? 0.f : 1.f;

  // uniform row offsets (clamped) + OOB masks; K pointers now, V later
  int rowoff[9];
  float okf[9];
  const float* krow[9];
#pragma unroll
  for (int dz = 0; dz < 3; ++dz)
#pragma unroll
    for (int dy = 0; dy < 3; ++dy) {
      int rr = dz * 3 + dy;
      int zz = d + dz - 1, yy = hu + dy - 1;
      bool ok = ((unsigned)zz < 64u) & ((unsigned)yy < 64u);
      int zc = zz < 0 ? 0 : (zz > 63 ? 63 : zz);
      int yc = yy < 0 ? 0 : (yy > 63 ? 63 : yy);
      rowoff[rr] = __builtin_amdgcn_readfirstlane(zc * S2 + yc * S);
      krow[rr] = Kb + rowoff[rr];
      okf[rr] = ok ? 1.f : 0.f;
    }
  int upos = d * S2 + hu * S;
  int pos = upos + lane;

  float sC[9], sXR[9], sXL[9];
#pragma unroll
  for (int rr = 0; rr < 9; ++rr) { sC[rr] = 0.f; sXR[rr] = 0.f; sXL[rr] = 0.f; }

  // ---- Phase A: QK tap scores + Q->bf16 LDS pack. ALL loads of the pair
  //      issue first (MLP ~40 with unroll 2), then the FMAs. ----
#pragma unroll 2
  for (int c2 = 0; c2 < CH; c2 += 2) {
    int coff0 = c2 * S3, coff1 = coff0 + S3;
    float q0 = Qb[coff0 + pos];
    float q1 = Qb[coff1 + pos];
    float rv0[9], rv1[9];
#pragma unroll
    for (int rr = 0; rr < 9; ++rr) rv0[rr] = krow[rr][coff0 + lane];
#pragma unroll
    for (int rr = 0; rr < 9; ++rr) rv1[rr] = krow[rr][coff1 + lane];

    float qR0 = __shfl_down(q0, 1), qL0 = __shfl_up(q0, 1);
    float qR1 = __shfl_down(q1, 1), qL1 = __shfl_up(q1, 1);
#pragma unroll
    for (int rr = 0; rr < 9; ++rr) {
      sC[rr]  = fmaf(q0,  rv0[rr], sC[rr]);
      sXR[rr] = fmaf(qR0, rv0[rr], sXR[rr]);
      sXL[rr] = fmaf(qL0, rv0[rr], sXL[rr]);
    }
#pragma unroll
    for (int rr = 0; rr < 9; ++rr) {
      sC[rr]  = fmaf(q1,  rv1[rr], sC[rr]);
      sXR[rr] = fmaf(qR1, rv1[rr], sXR[rr]);
      sXL[rr] = fmaf(qL1, rv1[rr], sXL[rr]);
    }
    unsigned int qpack =
        (unsigned int)f2bf(q0) | (((unsigned int)f2bf(q1)) << 16);
    *(unsigned int*)&xs[wv][lane][c2] = qpack;  // own slot, program-ordered
  }

  __asm__ __volatile__("" ::: "memory");
  __threadfence_block();

  // ---- pe-MFMA: spe[t][p] = peT[t][c] * Qbf[c][p] -> LDS float[64][33] ----
  {
    int n16 = lane & 15, g = lane >> 4;
    short8_t pfr[4];  // [mt][kc]
#pragma unroll
    for (int mt = 0; mt < 2; ++mt)
#pragma unroll
      for (int kc = 0; kc < 2; ++kc)
        pfr[mt * 2 + kc] =
            *(const short8_t*)(peT_buf + (mt * 16 + n16) * 64 + kc * 32 + g * 8);
    float* spf = (float*)&xs[wv][0][0];  // view: float[64][33] ([p][t])
#pragma unroll 1
    for (int nt = 0; nt < 4; ++nt) {
      const unsigned short* bp = &xs[wv][nt * 16 + n16][g * 8];
      union { short8_t v; uint2 h[2]; } u0, u1;
      u0.h[0] = *(const uint2*)(bp);
      u0.h[1] = *(const uint2*)(bp + 4);
      u1.h[0] = *(const uint2*)(bp + 32);
      u1.h[1] = *(const uint2*)(bp + 36);
#pragma unroll
      for (int mt = 0; mt < 2; ++mt) {
        float4_t acc = {0.f, 0.f, 0.f, 0.f};
        acc = __builtin_amdgcn_mfma_f32_16x16x32_bf16(pfr[mt * 2],     u0.v, acc, 0, 0, 0);
        acc = __builtin_amdgcn_mfma_f32_16x16x32_bf16(pfr[mt * 2 + 1], u1.v, acc, 0, 0, 0);
        // D: col(p)=n16, row(t)=mt*16+g*4+j -> write [p][t] rows this nt owns
#pragma unroll
        for (int j = 0; j < 4; ++j)
          spf[(nt * 16 + n16) * 33 + mt * 16 + g * 4 + j] = acc[j];
      }
    }
  }

  __asm__ __volatile__("" ::: "memory");
  __threadfence_block();

  // ---- assemble 27 tap scores; pe part read straight from LDS ----
  float s[27];
  {
    const float* spf = (const float*)&xs[wv][0][0];
    int sbase = lane * 33;
#pragma unroll
    for (int rr = 0; rr < 9; ++rr) {
      float lt = __shfl_up(sXR[rr], 1);
      float rt = __shfl_down(sXL[rr], 1);
      s[rr * 3]     = fmaf(lt * lmL, okf[rr], spf[sbase + rr * 3]);
      s[rr * 3 + 1] = fmaf(sC[rr],   okf[rr], spf[sbase + rr * 3 + 1]);
      s[rr * 3 + 2] = fmaf(rt * lmR, okf[rr], spf[sbase + rr * 3 + 2]);
    }
  }

  // ---- softmax (base-2; normalization folded into weights) ----
  const float SC = 0.125f * 1.44269504088896f;
#pragma unroll
  for (int t = 0; t < 27; ++t) s[t] *= SC;
  float m = s[0];
#pragma unroll
  for (int t = 1; t < 27; ++t) m = fmaxf(m, s[t]);
  float sum = 0.f;
#pragma unroll
  for (int t = 0; t < 27; ++t) {
    s[t] = exp2f(s[t] - m);
    sum += s[t];
  }
  float inv = 1.f / sum;

  // ---- weights + V row pointers (deferred live range) ----
  float wC[9], sLs[9], sRs[9];
  const float* vrow[9];
#pragma unroll
  for (int rr = 0; rr < 9; ++rr) {
    vrow[rr] = Vb + rowoff[rr];
    float f = inv * okf[rr];
    float wL = s[rr * 3] * f;
    wC[rr]   = s[rr * 3 + 1] * f;
    float wR = s[rr * 3 + 2] * f;
    sLs[rr] = __shfl_down(wL, 1);
    sRs[rr] = __shfl_up(wR, 1);
  }

  __asm__ __volatile__("" ::: "memory");
  __threadfence_block();

  // ---- Phase B: V-gather -> x bf16 -> own LDS row. Loads-first body. ----
#pragma unroll 2
  for (int c2 = 0; c2 < CH; c2 += 2) {
    int coff0 = c2 * S3, coff1 = coff0 + S3;
    float rv0[9], rv1[9];
#pragma unroll
    for (int rr = 0; rr < 9; ++rr) rv0[rr] = vrow[rr][coff0 + lane];
#pragma unroll
    for (int rr = 0; rr < 9; ++rr) rv1[rr] = vrow[rr][coff1 + lane];

    float own0 = 0.f, cR0 = 0.f, cL0 = 0.f;
    float own1 = 0.f, cR1 = 0.f, cL1 = 0.f;
#pragma unroll
    for (int rr = 0; rr < 9; ++rr) {
      own0 = fmaf(wC[rr],  rv0[rr], own0);
      cR0  = fmaf(sLs[rr], rv0[rr], cR0);
      cL0  = fmaf(sRs[rr], rv0[rr], cL0);
    }
#pragma unroll
    for (int rr = 0; rr < 9; ++rr) {
      own1 = fmaf(wC[rr],  rv1[rr], own1);
      cR1  = fmaf(sLs[rr], rv1[rr], cR1);
      cL1  = fmaf(sRs[rr], rv1[rr], cL1);
    }
    float x0 = own0 + __shfl_up(cR0, 1) * lmL + __shfl_down(cL0, 1) * lmR;
    float x1 = own1 + __shfl_up(cR1, 1) * lmL + __shfl_down(cL1, 1) * lmR;
    unsigned int packed =
        (unsigned int)f2bf(x0) | (((unsigned int)f2bf(x1)) << 16);
    *(unsigned int*)&xs[wv][lane][c2] = packed;
  }

  __asm__ __volatile__("" ::: "memory");
  __threadfence_block();

  // ---- Phase P: MFMA projection, ot-outer/pt-inner, minimal live frags ----
  {
    int n16 = lane & 15, g = lane >> 4;
#pragma unroll 1
    for (int ot = 0; ot < 4; ++ot) {
      short8_t a0 = *(const short8_t*)(WB_buf + (ot * 16 + n16) * CH + g * 8);
      short8_t a1 = *(const short8_t*)(WB_buf + (ot * 16 + n16) * CH + 32 + g * 8);
      int obase = ot * 16 + 4 * g;
      float4_t bv = *(const float4_t*)(bias + obase);
#pragma unroll 1
      for (int pt = 0; pt < 4; ++pt) {
        const unsigned short* bp = &xs[wv][pt * 16 + n16][g * 8];
        union { short8_t v; uint2 h[2]; } u0, u1;
        u0.h[0] = *(const uint2*)(bp);
        u0.h[1] = *(const uint2*)(bp + 4);
        u1.h[0] = *(const uint2*)(bp + 32);
        u1.h[1] = *(const uint2*)(bp + 36);
        float4_t acc = {0.f, 0.f, 0.f, 0.f};
        acc = __builtin_amdgcn_mfma_f32_16x16x32_bf16(a0, u0.v, acc, 0, 0, 0);
        acc = __builtin_amdgcn_mfma_f32_16x16x32_bf16(a1, u1.v, acc, 0, 0, 0);
#pragma unroll
        for (int j = 0; j < 4; ++j)
          outb[(obase + j) * S3 + upos + pt * 16 + n16] = acc[j] + bv[j];
      }
    }
  }
}

// ---------------------------------------------------------------------------
extern "C" void kernel_launch(void* const* d_in, const int* in_sizes, int n_in,
                              void* d_out, int out_size, void* d_ws, size_t ws_size,
                              hipStream_t stream) {
  const float* Q = (const float*)d_in[0];
  const float* K = (const float*)d_in[1];
  const float* V = (const float*)d_in[2];
  const float* pe = (const float*)d_in[3];
  const float* W = (const float*)d_in[4];
  const float* bias = (const float*)d_in[5];
  float* out = (float*)d_out;

  wprep<<<24, 256, 0, stream>>>(W, pe);
  attn_fused<<<2048, 256, 0, stream>>>(Q, K, V, bias, out);
}